// Round 2
// baseline (10887.684 us; speedup 1.0000x reference)
//
#include <hip/hip_runtime.h>
#include <stdint.h>

// LSTMClassifier on MI355X — round 14: cheap relaxed poll + per-wave rings.
// Round-13 evidence: k2 = 7.0 ms = 13.7 us/step vs ~1 us/step of real work
// (MfmaUtil ~1.4% on the active XCD). Remaining overhead was (a) ACQUIRE
// poll: buffer_inv + vmcnt(0) EVERY iteration x 128 polling waves, and
// (b) wg-wide __syncthreads + single flag per wg.
//
// Fixes:
//  (a) Poll with RELAXED agent loads (sc1 = L1 bypass, no buffer_inv).
//      Safe because hbuf addresses are write-once/read-once and advance
//      monotonically: a consumer L1 can never hold a stale h line — only
//      the flag needs L1 bypass. sched_barrier(0) pins h-loads below the
//      poll; HW can't issue them before the flag-value branch resolves.
//  (b) Per-WAVE rings: consumer wave w reads h rows [16w,16w+16), which are
//      written exclusively by producer wave w of each wg. So each of the 4
//      waves publishes its own flag with one RELEASE agent store (waits
//      only its own vmcnt) — NO __syncthreads in the scan loop at all.
//      flags becomes [513][128] (wave-major: w*32+g).
//  Bounded atomicAdd fallback kept as hang-safety (never fires normally).
//
// Workspace (50.8 MiB):
//   [0,4096)          int sync[]: [0]=leader, [8..16)=claim counters
//   [4096, +262.7KB)  int flags[513][128]    (memset 0 per launch)
//   [+, +33.6MB)      bf16 h_buf[513][64][512]  (h_buf[0] memset 0)
//   [+, +16.8MB)      bf16 e_seq[32768][256]

#define EMB   256
#define HID   512
#define NOUT  18
#define BATCH 64
#define SEQ   512
#define NPART 32     // scan workgroups = CUs on one XCD
#define WCOLS 16     // h-cols per wg (512/32)
#define FSTRIDE 128  // flags per step: 4 waves x 32 wgs

typedef __attribute__((ext_vector_type(8))) short bf16x8;
typedef __attribute__((ext_vector_type(4))) float floatx4;

__device__ inline float bf2f(short u) {
    union { float f; uint32_t i; } v;
    v.i = ((uint32_t)(uint16_t)u) << 16;
    return v.f;
}
__device__ inline short f2bf(float f) {
    union { float f; uint32_t i; } v; v.f = f;
    uint32_t r = v.i + 0x7fffu + ((v.i >> 16) & 1u);   // RNE
    return (short)(r >> 16);
}
__device__ inline float sigm(float x) { return 1.f / (1.f + __expf(-x)); }
__device__ inline float tanh_fast(float x) {
    float xc = fminf(fmaxf(x, -15.f), 15.f);
    float e  = __expf(2.f * xc);
    return (e - 1.f) / (e + 1.f);
}

// Detect packed-bf16 vs fp32 float tensors (verified round 4 — keep).
__device__ inline bool detect_bf16(const void* emb_raw) {
    const uint32_t* w = (const uint32_t*)emb_raw;
    int votes = 0;
    #pragma unroll
    for (int i = 0; i < 8; i++) {
        uint32_t e = (w[i] >> 7) & 0xFFu;
        votes += (e >= 110u && e <= 135u) ? 1 : 0;
    }
    return votes >= 6;
}
__device__ inline float rd(const void* p, int idx, bool isbf) {
    return isbf ? bf2f(((const short*)p)[idx]) : ((const float*)p)[idx];
}

// load one 8-element bf16 fragment from a maybe-fp32 weight row
__device__ inline bf16x8 ldfrag(const void* base, size_t off, bool isbf) {
    if (isbf) return *(const bf16x8*)((const short*)base + off);
    const float* s = (const float*)base + off;
    bf16x8 v;
    #pragma unroll
    for (int j = 0; j < 8; j++) v[j] = f2bf(s[j]);
    return v;
}

// ---------------------------------------------------------------------------
// K0: e_seq[u][k] = emb[x[u&63][u>>6]][k] (bf16 out), u = s*64+b.
// ---------------------------------------------------------------------------
__global__ __launch_bounds__(256) void k0_gather(
    const int* __restrict__ x, const void* __restrict__ emb,
    short* __restrict__ eseq)
{
    const bool isbf = detect_bf16(emb);
    const int u0 = blockIdx.x * 32;
    #pragma unroll
    for (int it = 0; it < 4; it++) {
        int idx = it * 256 + threadIdx.x;          // 0..1023
        int u   = u0 + (idx >> 5);
        int ch  = (idx & 31) * 8;
        int tok = x[(u & 63) * SEQ + (u >> 6)];
        bf16x8 v;
        if (isbf) {
            v = *(const bf16x8*)((const short*)emb + (size_t)tok * EMB + ch);
        } else {
            const float* src = (const float*)emb + (size_t)tok * EMB + ch;
            #pragma unroll
            for (int j = 0; j < 8; j++) v[j] = f2bf(src[j]);
        }
        *(bf16x8*)(eseq + (size_t)u * EMB + ch) = v;
    }
}

// ---------------------------------------------------------------------------
// K2: intra-XCD persistent scan, register weights, per-wave relaxed-poll
// rings. 32 wgs; wg g owns h cols [16g,16g+16); wave w owns h rows
// [16w,16w+16) of its wg's columns, and depends only on wave w of every wg.
// ---------------------------------------------------------------------------
__global__ __launch_bounds__(256, 1) void k2_lstm(
    const void* __restrict__ w_hh, const void* __restrict__ w_ih,
    const void* __restrict__ b_ih, const void* __restrict__ b_hh,
    const void* __restrict__ emb, const short* __restrict__ eseq,
    short* __restrict__ hbuf, int* __restrict__ sync, int* __restrict__ flags)
{
    __shared__ float biasl[64];
    __shared__ int   sh_slot;

    const int t = threadIdx.x;

    // ---- XCD leader claim (round-9/10 verified; startup only).
    // Pigeonhole: 8*31 = 248 < 256 grid => some XCD always reaches NPART. ----
    if (t == 0) {
        unsigned xcd;
        asm volatile("s_getreg_b32 %0, hwreg(HW_REG_XCC_ID)" : "=s"(xcd));
        xcd &= 7u;
        int c = atomicAdd(&sync[8 + xcd], 1);
        if (c == NPART - 1) atomicCAS(&sync[0], 0, (int)xcd + 1);
        int L;
        while ((L = atomicAdd(&sync[0], 0)) == 0)
            __builtin_amdgcn_s_sleep(8);
        sh_slot = (L == (int)xcd + 1 && c < NPART) ? c : -1;
    }
    __syncthreads();
    const int g = sh_slot;
    if (g < 0) return;

    const bool isbf = detect_bf16(emb);
    const int lane = t & 63;
    const int w    = t >> 6;
    const int col  = lane & 15;
    const int quad = lane >> 4;

    // ---- B fragments to registers: breg[nt][kk], 96 x bf16x8 ----
    bf16x8 breg[4][24];
    #pragma unroll
    for (int nt = 0; nt < 4; nt++) {
        const size_t grow = (size_t)(nt * HID + g * WCOLS + col);
        #pragma unroll
        for (int kk = 0; kk < 16; kk++)
            breg[nt][kk] = ldfrag(w_hh, grow * HID + kk * 32 + quad * 8, isbf);
        #pragma unroll
        for (int kk = 0; kk < 8; kk++)
            breg[nt][16 + kk] = ldfrag(w_ih, grow * EMB + kk * 32 + quad * 8, isbf);
    }
    if (t < 64) {
        int grow = (t >> 4) * HID + g * WCOLS + (t & 15);
        biasl[t] = rd(b_ih, grow, isbf) + rd(b_hh, grow, isbf);
    }
    __syncthreads();
    const float bI = biasl[col],      bF = biasl[16 + col];
    const float bG = biasl[32 + col], bO = biasl[48 + col];

    float cre[4] = {0.f, 0.f, 0.f, 0.f};

    const short* eptr = eseq + (size_t)(w * 16 + col) * EMB + quad * 8;
    const short* hrd  = hbuf + (size_t)(w * 16 + col) * HID + quad * 8;
    short*       hwr  = hbuf + (size_t)(BATCH * HID)
                      + (size_t)(w * 16 + quad * 4) * HID + g * WCOLS + col;

    // ---- scan: NO intra-wg barriers; 4 independent per-wave rings ----
    for (int step = 0; step < SEQ; step++) {
        // e A-frags + e-projection MFMAs: independent of the handshake —
        // they burn while we'd otherwise wait for the flags.
        bf16x8 ae[8];
        #pragma unroll
        for (int kk = 0; kk < 8; kk++)
            ae[kk] = *(const bf16x8*)(eptr + kk * 32);

        floatx4 a0 = (floatx4){0.f,0.f,0.f,0.f}, a1 = a0, a2 = a0, a3 = a0;
        #pragma unroll
        for (int kk = 0; kk < 8; kk++) {
            a0 = __builtin_amdgcn_mfma_f32_16x16x32_bf16(ae[kk], breg[0][16+kk], a0, 0,0,0);
            a1 = __builtin_amdgcn_mfma_f32_16x16x32_bf16(ae[kk], breg[1][16+kk], a1, 0,0,0);
            a2 = __builtin_amdgcn_mfma_f32_16x16x32_bf16(ae[kk], breg[2][16+kk], a2, 0,0,0);
            a3 = __builtin_amdgcn_mfma_f32_16x16x32_bf16(ae[kk], breg[3][16+kk], a3, 0,0,0);
        }

        // wait: lanes 0..31 poll the 32 same-wave producer flags with RELAXED
        // agent loads (sc1 = L1 bypass, NO buffer_inv — h lines can't be L1-
        // stale: write-once addresses, first touch is post-publication).
        // Bounded; RMW fallback guarantees progress.
        if (step > 0 && lane < NPART) {
            int* fp = flags + (size_t)step * FSTRIDE + w * NPART + lane;
            int iters = 0;
            while (__hip_atomic_load(fp, __ATOMIC_RELAXED,
                                     __HIP_MEMORY_SCOPE_AGENT) == 0) {
                if (++iters > 8192) {
                    while (atomicAdd(fp, 0) == 0)
                        __builtin_amdgcn_s_sleep(8);
                    break;
                }
            }
        }
        __builtin_amdgcn_sched_barrier(0);   // keep h-loads below the poll

        // issue BOTH h windows back-to-back; window-2 latency hides under
        // window-1 MFMAs
        bf16x8 ah[8], ah2[8];
        #pragma unroll
        for (int kk = 0; kk < 8; kk++)
            ah[kk]  = *(const bf16x8*)(hrd + kk * 32);
        #pragma unroll
        for (int kk = 0; kk < 8; kk++)
            ah2[kk] = *(const bf16x8*)(hrd + (8 + kk) * 32);
        #pragma unroll
        for (int kk = 0; kk < 8; kk++) {
            a0 = __builtin_amdgcn_mfma_f32_16x16x32_bf16(ah[kk], breg[0][kk], a0, 0,0,0);
            a1 = __builtin_amdgcn_mfma_f32_16x16x32_bf16(ah[kk], breg[1][kk], a1, 0,0,0);
            a2 = __builtin_amdgcn_mfma_f32_16x16x32_bf16(ah[kk], breg[2][kk], a2, 0,0,0);
            a3 = __builtin_amdgcn_mfma_f32_16x16x32_bf16(ah[kk], breg[3][kk], a3, 0,0,0);
        }
        #pragma unroll
        for (int kk = 0; kk < 8; kk++) {
            a0 = __builtin_amdgcn_mfma_f32_16x16x32_bf16(ah2[kk], breg[0][8+kk], a0, 0,0,0);
            a1 = __builtin_amdgcn_mfma_f32_16x16x32_bf16(ah2[kk], breg[1][8+kk], a1, 0,0,0);
            a2 = __builtin_amdgcn_mfma_f32_16x16x32_bf16(ah2[kk], breg[2][8+kk], a2, 0,0,0);
            a3 = __builtin_amdgcn_mfma_f32_16x16x32_bf16(ah2[kk], breg[3][8+kk], a3, 0,0,0);
        }

        // in-register epilogue
        #pragma unroll
        for (int r = 0; r < 4; r++) {
            float iv = sigm(a0[r] + bI);
            float fv = sigm(a1[r] + bF);
            float gv = tanh_fast(a2[r] + bG);
            float ov = sigm(a3[r] + bO);
            cre[r] = fv * cre[r] + iv * gv;
            float h = ov * tanh_fast(cre[r]);
            hwr[(size_t)r * HID] = f2bf(h);
        }

        // per-wave publish: RELEASE waits THIS wave's vmcnt (the 4 h-stores),
        // then the flag store lands in L2. Consumers only need this wave's
        // rows, so no wg barrier is required.
        if (lane == 0)
            __hip_atomic_store(flags + (size_t)(step + 1) * FSTRIDE + w * NPART + g,
                               1, __ATOMIC_RELEASE, __HIP_MEMORY_SCOPE_AGENT);

        eptr += (size_t)BATCH * EMB;
        hrd  += (size_t)BATCH * HID;
        hwr  += (size_t)BATCH * HID;
    }
}

// ---------------------------------------------------------------------------
// K3: logits = h_seq * W_fc^T + b_fc -> log_softmax(18). One token per thread.
// ---------------------------------------------------------------------------
__global__ __launch_bounds__(256) void k3_logits(
    const short* __restrict__ hbuf, const void* __restrict__ w_fc,
    const void* __restrict__ b_fc, const void* __restrict__ emb,
    void* __restrict__ out)
{
    __shared__ float Wf[NOUT][516];
    const bool isbf = detect_bf16(emb);
    const int t = threadIdx.x;
    for (int idx = t; idx < NOUT * 64; idx += 256) {
        int o = idx >> 6, ch = (idx & 63) * 8;
        #pragma unroll
        for (int j = 0; j < 8; j++)
            Wf[o][ch + j] = rd(w_fc, o * HID + ch + j, isbf);
    }
    __syncthreads();

    int u = blockIdx.x * 256 + t;              // u = s*64+b
    const short* hp = hbuf + (size_t)(u + BATCH) * HID;

    float acc[NOUT];
    #pragma unroll
    for (int o = 0; o < NOUT; o++) acc[o] = rd(b_fc, o, isbf);

    for (int ch = 0; ch < HID; ch += 8) {
        bf16x8 h8 = *(const bf16x8*)(hp + ch);
        float hf[8];
        #pragma unroll
        for (int j = 0; j < 8; j++) hf[j] = bf2f(h8[j]);
        #pragma unroll
        for (int o = 0; o < NOUT; o++) {
            floatx4 wa = *(const floatx4*)&Wf[o][ch];
            floatx4 wb = *(const floatx4*)&Wf[o][ch + 4];
            acc[o] += hf[0] * wa[0] + hf[1] * wa[1] + hf[2] * wa[2] + hf[3] * wa[3]
                    + hf[4] * wb[0] + hf[5] * wb[1] + hf[6] * wb[2] + hf[7] * wb[3];
        }
    }

    float mx = acc[0];
    #pragma unroll
    for (int o = 1; o < NOUT; o++) mx = fmaxf(mx, acc[o]);
    float s = 0.f;
    #pragma unroll
    for (int o = 0; o < NOUT; o++) s += __expf(acc[o] - mx);
    float lse = mx + __logf(s);

    int b = u & 63, sq = u >> 6;
    size_t base = (size_t)b * (SEQ * NOUT) + (size_t)sq * NOUT;
    if (isbf) {
        short* op = (short*)out + base;
        #pragma unroll
        for (int o = 0; o < NOUT; o++) op[o] = f2bf(acc[o] - lse);
    } else {
        float* op = (float*)out + base;
        #pragma unroll
        for (int o = 0; o < NOUT; o++) op[o] = acc[o] - lse;
    }
}

// ---------------------------------------------------------------------------
extern "C" void kernel_launch(void* const* d_in, const int* in_sizes, int n_in,
                              void* d_out, int out_size, void* d_ws, size_t ws_size,
                              hipStream_t stream) {
    const int*  x   = (const int*)d_in[0];
    const void* emb = d_in[1];
    const void* wih = d_in[2];
    const void* whh = d_in[3];
    const void* bih = d_in[4];
    const void* bhh = d_in[5];
    const void* wfc = d_in[6];
    const void* bfc = d_in[7];

    char*  ws    = (char*)d_ws;
    int*   sync  = (int*)ws;
    int*   flags = (int*)(ws + 4096);
    const size_t flagsz = (size_t)(SEQ + 1) * FSTRIDE * sizeof(int);  // 262.7 KB
    short* hbuf  = (short*)(ws + 4096 + ((flagsz + 255) & ~(size_t)255));
    short* eseq  = (short*)((char*)hbuf + (size_t)(SEQ + 1) * BATCH * HID * 2);

    (void)hipMemsetAsync(sync, 0, 4096, stream);                    // claim
    (void)hipMemsetAsync(flags, 0, flagsz, stream);                 // flags = 0
    (void)hipMemsetAsync(hbuf, 0, (size_t)BATCH * HID * 2, stream); // h_0 = 0

    k0_gather<<<1024, 256, 0, stream>>>(x, emb, eseq);
    k2_lstm<<<256, 256, 0, stream>>>(whh, wih, bih, bhh, emb, eseq,
                                     hbuf, sync, flags);
    k3_logits<<<128, 256, 0, stream>>>(hbuf, wfc, bfc, emb, d_out);
}

// Round 3
// 3177.121 us; speedup vs baseline: 3.4269x; 3.4269x over previous
//
#include <hip/hip_runtime.h>
#include <stdint.h>

// LSTMClassifier on MI355X — round 15: weights in LDS (the real fix).
// Round-14 post-mortem: VGPR_Count=228 but breg[4][24] alone needs 384 VGPRs
// => the compiler NEVER kept weights in registers; it sank the ldfrag loads
// (fp32 loads + f2bf converts!) into the scan loop. Every step re-read 196KB
// of fp32 weights per wg from L1/L2 and re-converted — ~10us/step of hidden
// work, matching the 13.7-22us/step measurements. R14's regression on top:
// per-wave RELEASE-agent stores (L2 writeback) + unsynced-wave L1 thrash.
//
// Fixes:
//  (1) Stage this wg's weight share (64 gate-rows x 768 K) in LDS as bf16,
//      converted ONCE at startup: 96KB < 160KB. Per-step B reads are LDS
//      (ds_read_b128, ~1.3us/CU/step, overlaps MFMA). Residency guaranteed.
//  (2) Sync (proven R13 barrier structure, cheap flavor): wave0-only RELAXED
//      agent poll (sc1 L1-bypass, NO buffer_inv per iter), __syncthreads
//      (drains each wave's vmcnt before s_barrier => all h-stores in L2),
//      then ONE relaxed-agent flag store per wg (no buffer_wbl2).
//      h lines can't be L1-stale (write-once addresses, first touch is
//      post-publication) — relaxed is sufficient; R14 proved correctness.
//  Bounded atomicAdd fallback kept as hang-safety.
//
// Workspace (50.6 MiB): unchanged layout (flags stride back to 64).

#define EMB   256
#define HID   512
#define NOUT  18
#define BATCH 64
#define SEQ   512
#define NPART 32     // scan workgroups = CUs on one XCD
#define WCOLS 16     // h-cols per wg (512/32)

typedef __attribute__((ext_vector_type(8))) short bf16x8;
typedef __attribute__((ext_vector_type(4))) float floatx4;

__device__ inline float bf2f(short u) {
    union { float f; uint32_t i; } v;
    v.i = ((uint32_t)(uint16_t)u) << 16;
    return v.f;
}
__device__ inline short f2bf(float f) {
    union { float f; uint32_t i; } v; v.f = f;
    uint32_t r = v.i + 0x7fffu + ((v.i >> 16) & 1u);   // RNE
    return (short)(r >> 16);
}
__device__ inline float sigm(float x) { return 1.f / (1.f + __expf(-x)); }
__device__ inline float tanh_fast(float x) {
    float xc = fminf(fmaxf(x, -15.f), 15.f);
    float e  = __expf(2.f * xc);
    return (e - 1.f) / (e + 1.f);
}

// Detect packed-bf16 vs fp32 float tensors (verified round 4 — keep).
__device__ inline bool detect_bf16(const void* emb_raw) {
    const uint32_t* w = (const uint32_t*)emb_raw;
    int votes = 0;
    #pragma unroll
    for (int i = 0; i < 8; i++) {
        uint32_t e = (w[i] >> 7) & 0xFFu;
        votes += (e >= 110u && e <= 135u) ? 1 : 0;
    }
    return votes >= 6;
}
__device__ inline float rd(const void* p, int idx, bool isbf) {
    return isbf ? bf2f(((const short*)p)[idx]) : ((const float*)p)[idx];
}

// load one 8-element bf16 fragment from a maybe-fp32 weight row
__device__ inline bf16x8 ldfrag(const void* base, size_t off, bool isbf) {
    if (isbf) return *(const bf16x8*)((const short*)base + off);
    const float* s = (const float*)base + off;
    bf16x8 v;
    #pragma unroll
    for (int j = 0; j < 8; j++) v[j] = f2bf(s[j]);
    return v;
}

// ---------------------------------------------------------------------------
// K0: e_seq[u][k] = emb[x[u&63][u>>6]][k] (bf16 out), u = s*64+b.
// ---------------------------------------------------------------------------
__global__ __launch_bounds__(256) void k0_gather(
    const int* __restrict__ x, const void* __restrict__ emb,
    short* __restrict__ eseq)
{
    const bool isbf = detect_bf16(emb);
    const int u0 = blockIdx.x * 32;
    #pragma unroll
    for (int it = 0; it < 4; it++) {
        int idx = it * 256 + threadIdx.x;          // 0..1023
        int u   = u0 + (idx >> 5);
        int ch  = (idx & 31) * 8;
        int tok = x[(u & 63) * SEQ + (u >> 6)];
        bf16x8 v;
        if (isbf) {
            v = *(const bf16x8*)((const short*)emb + (size_t)tok * EMB + ch);
        } else {
            const float* src = (const float*)emb + (size_t)tok * EMB + ch;
            #pragma unroll
            for (int j = 0; j < 8; j++) v[j] = f2bf(src[j]);
        }
        *(bf16x8*)(eseq + (size_t)u * EMB + ch) = v;
    }
}

// ---------------------------------------------------------------------------
// K2: intra-XCD persistent scan. Weights live in LDS (bf16, 96KB), loaded
// once. 32 wgs; wg g owns h cols [16g,16g+16). Barrier-per-step, wave0 polls.
// ---------------------------------------------------------------------------
__global__ __launch_bounds__(256, 1) void k2_lstm(
    const void* __restrict__ w_hh, const void* __restrict__ w_ih,
    const void* __restrict__ b_ih, const void* __restrict__ b_hh,
    const void* __restrict__ emb, const short* __restrict__ eseq,
    short* __restrict__ hbuf, int* __restrict__ sync, int* __restrict__ flags)
{
    // 96 slots (nt*24+kk) x 64 lanes x 16B = 98,304 B of bf16 weight frags
    __shared__ short lds_w[96 * 64 * 8];
    __shared__ float biasl[64];
    __shared__ int   sh_slot;

    const int t = threadIdx.x;

    // ---- XCD leader claim (round-9/10 verified; startup only).
    // Pigeonhole: 8*31 = 248 < 256 grid => some XCD always reaches NPART. ----
    if (t == 0) {
        unsigned xcd;
        asm volatile("s_getreg_b32 %0, hwreg(HW_REG_XCC_ID)" : "=s"(xcd));
        xcd &= 7u;
        int c = atomicAdd(&sync[8 + xcd], 1);
        if (c == NPART - 1) atomicCAS(&sync[0], 0, (int)xcd + 1);
        int L;
        while ((L = atomicAdd(&sync[0], 0)) == 0)
            __builtin_amdgcn_s_sleep(8);
        sh_slot = (L == (int)xcd + 1 && c < NPART) ? c : -1;
    }
    __syncthreads();
    const int g = sh_slot;
    if (g < 0) return;

    const bool isbf = detect_bf16(emb);
    const int lane = t & 63;
    const int w    = t >> 6;
    const int col  = lane & 15;
    const int quad = lane >> 4;

    // ---- stage weight fragments into LDS (bf16), once ----
    // slot = nt*24 + kk; kk 0..15 = W_hh (k=kk*32+q*8), kk 16..23 = W_ih.
    for (int item = t; item < 96 * 64; item += 256) {
        int slot = item >> 6;
        int ln   = item & 63;
        int nt   = slot / 24;
        int kk   = slot % 24;
        int c    = ln & 15, q = ln >> 4;
        size_t grow = (size_t)(nt * HID + g * WCOLS + c);
        bf16x8 v;
        if (kk < 16) v = ldfrag(w_hh, grow * HID + kk * 32 + q * 8, isbf);
        else         v = ldfrag(w_ih, grow * EMB + (kk - 16) * 32 + q * 8, isbf);
        *(bf16x8*)(lds_w + (size_t)item * 8) = v;
    }
    if (t < 64) {
        int grow = (t >> 4) * HID + g * WCOLS + (t & 15);
        biasl[t] = rd(b_ih, grow, isbf) + rd(b_hh, grow, isbf);
    }
    __syncthreads();
    const float bI = biasl[col],      bF = biasl[16 + col];
    const float bG = biasl[32 + col], bO = biasl[48 + col];

    // per-lane base into the LDS frag table
    const short* lwl = lds_w + lane * 8;
#define LWF(nt, kk) (*(const bf16x8*)(lwl + (size_t)(((nt) * 24 + (kk)) * 64) * 8))

    float cre[4] = {0.f, 0.f, 0.f, 0.f};

    const short* eptr = eseq + (size_t)(w * 16 + col) * EMB + quad * 8;
    const short* hrd  = hbuf + (size_t)(w * 16 + col) * HID + quad * 8;
    short*       hwr  = hbuf + (size_t)(BATCH * HID)
                      + (size_t)(w * 16 + quad * 4) * HID + g * WCOLS + col;

    // ---- scan ----
    for (int step = 0; step < SEQ; step++) {
        // e A-frags + e-projection MFMAs (handshake-independent): run before
        // the poll so the flag round trip hides under real work.
        bf16x8 ae[8];
        #pragma unroll
        for (int kk = 0; kk < 8; kk++)
            ae[kk] = *(const bf16x8*)(eptr + kk * 32);

        floatx4 a0 = (floatx4){0.f,0.f,0.f,0.f}, a1 = a0, a2 = a0, a3 = a0;
        #pragma unroll
        for (int kk = 0; kk < 8; kk++) {
            a0 = __builtin_amdgcn_mfma_f32_16x16x32_bf16(ae[kk], LWF(0, 16+kk), a0, 0,0,0);
            a1 = __builtin_amdgcn_mfma_f32_16x16x32_bf16(ae[kk], LWF(1, 16+kk), a1, 0,0,0);
            a2 = __builtin_amdgcn_mfma_f32_16x16x32_bf16(ae[kk], LWF(2, 16+kk), a2, 0,0,0);
            a3 = __builtin_amdgcn_mfma_f32_16x16x32_bf16(ae[kk], LWF(3, 16+kk), a3, 0,0,0);
        }

        // wave0's lanes 0..31 poll the 32 producer flags (RELAXED agent =
        // sc1 L1-bypass, no buffer_inv). Other waves wait at the barrier.
        if (step > 0 && w == 0 && lane < NPART) {
            int* fp = flags + (size_t)step * 64 + lane;
            int iters = 0;
            while (__hip_atomic_load(fp, __ATOMIC_RELAXED,
                                     __HIP_MEMORY_SCOPE_AGENT) == 0) {
                if (++iters > 16384) {
                    while (atomicAdd(fp, 0) == 0)
                        __builtin_amdgcn_s_sleep(8);
                    break;
                }
            }
        }
        __builtin_amdgcn_sched_barrier(0);
        __syncthreads();       // all waves: h(step-1) is published & in L2

        // issue BOTH h windows back-to-back; window-2 latency hides under
        // window-1 MFMAs
        bf16x8 ah[8], ah2[8];
        #pragma unroll
        for (int kk = 0; kk < 8; kk++)
            ah[kk]  = *(const bf16x8*)(hrd + kk * 32);
        #pragma unroll
        for (int kk = 0; kk < 8; kk++)
            ah2[kk] = *(const bf16x8*)(hrd + (8 + kk) * 32);
        #pragma unroll
        for (int kk = 0; kk < 8; kk++) {
            a0 = __builtin_amdgcn_mfma_f32_16x16x32_bf16(ah[kk], LWF(0, kk), a0, 0,0,0);
            a1 = __builtin_amdgcn_mfma_f32_16x16x32_bf16(ah[kk], LWF(1, kk), a1, 0,0,0);
            a2 = __builtin_amdgcn_mfma_f32_16x16x32_bf16(ah[kk], LWF(2, kk), a2, 0,0,0);
            a3 = __builtin_amdgcn_mfma_f32_16x16x32_bf16(ah[kk], LWF(3, kk), a3, 0,0,0);
        }
        #pragma unroll
        for (int kk = 0; kk < 8; kk++) {
            a0 = __builtin_amdgcn_mfma_f32_16x16x32_bf16(ah2[kk], LWF(0, 8+kk), a0, 0,0,0);
            a1 = __builtin_amdgcn_mfma_f32_16x16x32_bf16(ah2[kk], LWF(1, 8+kk), a1, 0,0,0);
            a2 = __builtin_amdgcn_mfma_f32_16x16x32_bf16(ah2[kk], LWF(2, 8+kk), a2, 0,0,0);
            a3 = __builtin_amdgcn_mfma_f32_16x16x32_bf16(ah2[kk], LWF(3, 8+kk), a3, 0,0,0);
        }

        // in-register epilogue
        #pragma unroll
        for (int r = 0; r < 4; r++) {
            float iv = sigm(a0[r] + bI);
            float fv = sigm(a1[r] + bF);
            float gv = tanh_fast(a2[r] + bG);
            float ov = sigm(a3[r] + bO);
            cre[r] = fv * cre[r] + iv * gv;
            float h = ov * tanh_fast(cre[r]);
            hwr[(size_t)r * HID] = f2bf(h);
        }

        // __syncthreads drains every wave's vmcnt before s_barrier => all
        // 256 threads' h-stores are committed to L2 when t0 publishes.
        __syncthreads();
        if (t == 0)
            __hip_atomic_store(flags + (size_t)(step + 1) * 64 + g, 1,
                               __ATOMIC_RELAXED, __HIP_MEMORY_SCOPE_AGENT);

        eptr += (size_t)BATCH * EMB;
        hrd  += (size_t)BATCH * HID;
        hwr  += (size_t)BATCH * HID;
    }
#undef LWF
}

// ---------------------------------------------------------------------------
// K3: logits = h_seq * W_fc^T + b_fc -> log_softmax(18). One token per thread.
// ---------------------------------------------------------------------------
__global__ __launch_bounds__(256) void k3_logits(
    const short* __restrict__ hbuf, const void* __restrict__ w_fc,
    const void* __restrict__ b_fc, const void* __restrict__ emb,
    void* __restrict__ out)
{
    __shared__ float Wf[NOUT][516];
    const bool isbf = detect_bf16(emb);
    const int t = threadIdx.x;
    for (int idx = t; idx < NOUT * 64; idx += 256) {
        int o = idx >> 6, ch = (idx & 63) * 8;
        #pragma unroll
        for (int j = 0; j < 8; j++)
            Wf[o][ch + j] = rd(w_fc, o * HID + ch + j, isbf);
    }
    __syncthreads();

    int u = blockIdx.x * 256 + t;              // u = s*64+b
    const short* hp = hbuf + (size_t)(u + BATCH) * HID;

    float acc[NOUT];
    #pragma unroll
    for (int o = 0; o < NOUT; o++) acc[o] = rd(b_fc, o, isbf);

    for (int ch = 0; ch < HID; ch += 8) {
        bf16x8 h8 = *(const bf16x8*)(hp + ch);
        float hf[8];
        #pragma unroll
        for (int j = 0; j < 8; j++) hf[j] = bf2f(h8[j]);
        #pragma unroll
        for (int o = 0; o < NOUT; o++) {
            floatx4 wa = *(const floatx4*)&Wf[o][ch];
            floatx4 wb = *(const floatx4*)&Wf[o][ch + 4];
            acc[o] += hf[0] * wa[0] + hf[1] * wa[1] + hf[2] * wa[2] + hf[3] * wa[3]
                    + hf[4] * wb[0] + hf[5] * wb[1] + hf[6] * wb[2] + hf[7] * wb[3];
        }
    }

    float mx = acc[0];
    #pragma unroll
    for (int o = 1; o < NOUT; o++) mx = fmaxf(mx, acc[o]);
    float s = 0.f;
    #pragma unroll
    for (int o = 0; o < NOUT; o++) s += __expf(acc[o] - mx);
    float lse = mx + __logf(s);

    int b = u & 63, sq = u >> 6;
    size_t base = (size_t)b * (SEQ * NOUT) + (size_t)sq * NOUT;
    if (isbf) {
        short* op = (short*)out + base;
        #pragma unroll
        for (int o = 0; o < NOUT; o++) op[o] = f2bf(acc[o] - lse);
    } else {
        float* op = (float*)out + base;
        #pragma unroll
        for (int o = 0; o < NOUT; o++) op[o] = acc[o] - lse;
    }
}

// ---------------------------------------------------------------------------
extern "C" void kernel_launch(void* const* d_in, const int* in_sizes, int n_in,
                              void* d_out, int out_size, void* d_ws, size_t ws_size,
                              hipStream_t stream) {
    const int*  x   = (const int*)d_in[0];
    const void* emb = d_in[1];
    const void* wih = d_in[2];
    const void* whh = d_in[3];
    const void* bih = d_in[4];
    const void* bhh = d_in[5];
    const void* wfc = d_in[6];
    const void* bfc = d_in[7];

    char*  ws    = (char*)d_ws;
    int*   sync  = (int*)ws;
    int*   flags = (int*)(ws + 4096);
    const size_t flagsz = (size_t)(SEQ + 1) * 64 * sizeof(int);   // 131.3 KB
    short* hbuf  = (short*)(ws + 4096 + ((flagsz + 255) & ~(size_t)255));
    short* eseq  = (short*)((char*)hbuf + (size_t)(SEQ + 1) * BATCH * HID * 2);

    (void)hipMemsetAsync(sync, 0, 4096, stream);                    // claim
    (void)hipMemsetAsync(flags, 0, flagsz, stream);                 // flags = 0
    (void)hipMemsetAsync(hbuf, 0, (size_t)BATCH * HID * 2, stream); // h_0 = 0

    k0_gather<<<1024, 256, 0, stream>>>(x, emb, eseq);
    k2_lstm<<<256, 256, 0, stream>>>(whh, wih, bih, bhh, emb, eseq,
                                     hbuf, sync, flags);
    k3_logits<<<128, 256, 0, stream>>>(hbuf, wfc, bfc, emb, d_out);
}

// Round 4
// 2439.663 us; speedup vs baseline: 4.4628x; 1.3023x over previous
//
#include <hip/hip_runtime.h>
#include <stdint.h>

// LSTMClassifier on MI355X — round 16: 8 waves/wg, K-split, TLP x2.
// R15 evidence: 7.1 us/step with Occupancy = 1 wave/SIMD. Accounting:
// LDS B-frag floor ~1.9us + sync ~0.6us; the other ~4us is exposed latency
// (ds_read ~120cy, global h/e 200-700cy, barrier skew) with zero TLP to
// hide it. Fix: 512-thread wgs = 2 waves/SIMD. Wave pairs split K:
//   waves 0-3 (batch quadrant q=w):   e-chunks 0-3 + h-chunks 0-7
//   waves 4-7 (batch quadrant q=w-4): e-chunks 4-7 + h-chunks 8-15
// Both halves have pre-poll e-MFMAs (poll hidden on every SIMD); post-poll
// chain halves (32 MFMA+ds per wave). Waves 4-7 dump partial accs to a
// 16KB LDS xbuf; waves 0-3 add + run the unchanged in-register epilogue.
// Numerics: one extra fp32 add per acc (~1e-7 rel) — negligible.
// LDS 96+16KB => still 1 wg/CU, 256-grid claim logic unchanged.
//
// Workspace (50.6 MiB): unchanged layout.

#define EMB   256
#define HID   512
#define NOUT  18
#define BATCH 64
#define SEQ   512
#define NPART 32     // scan workgroups = CUs on one XCD
#define WCOLS 16     // h-cols per wg (512/32)

typedef __attribute__((ext_vector_type(8))) short bf16x8;
typedef __attribute__((ext_vector_type(4))) float floatx4;

__device__ inline float bf2f(short u) {
    union { float f; uint32_t i; } v;
    v.i = ((uint32_t)(uint16_t)u) << 16;
    return v.f;
}
__device__ inline short f2bf(float f) {
    union { float f; uint32_t i; } v; v.f = f;
    uint32_t r = v.i + 0x7fffu + ((v.i >> 16) & 1u);   // RNE
    return (short)(r >> 16);
}
__device__ inline float sigm(float x) { return 1.f / (1.f + __expf(-x)); }
__device__ inline float tanh_fast(float x) {
    float xc = fminf(fmaxf(x, -15.f), 15.f);
    float e  = __expf(2.f * xc);
    return (e - 1.f) / (e + 1.f);
}

// Detect packed-bf16 vs fp32 float tensors (verified round 4 — keep).
__device__ inline bool detect_bf16(const void* emb_raw) {
    const uint32_t* w = (const uint32_t*)emb_raw;
    int votes = 0;
    #pragma unroll
    for (int i = 0; i < 8; i++) {
        uint32_t e = (w[i] >> 7) & 0xFFu;
        votes += (e >= 110u && e <= 135u) ? 1 : 0;
    }
    return votes >= 6;
}
__device__ inline float rd(const void* p, int idx, bool isbf) {
    return isbf ? bf2f(((const short*)p)[idx]) : ((const float*)p)[idx];
}

// load one 8-element bf16 fragment from a maybe-fp32 weight row
__device__ inline bf16x8 ldfrag(const void* base, size_t off, bool isbf) {
    if (isbf) return *(const bf16x8*)((const short*)base + off);
    const float* s = (const float*)base + off;
    bf16x8 v;
    #pragma unroll
    for (int j = 0; j < 8; j++) v[j] = f2bf(s[j]);
    return v;
}

// ---------------------------------------------------------------------------
// K0: e_seq[u][k] = emb[x[u&63][u>>6]][k] (bf16 out), u = s*64+b.
// ---------------------------------------------------------------------------
__global__ __launch_bounds__(256) void k0_gather(
    const int* __restrict__ x, const void* __restrict__ emb,
    short* __restrict__ eseq)
{
    const bool isbf = detect_bf16(emb);
    const int u0 = blockIdx.x * 32;
    #pragma unroll
    for (int it = 0; it < 4; it++) {
        int idx = it * 256 + threadIdx.x;          // 0..1023
        int u   = u0 + (idx >> 5);
        int ch  = (idx & 31) * 8;
        int tok = x[(u & 63) * SEQ + (u >> 6)];
        bf16x8 v;
        if (isbf) {
            v = *(const bf16x8*)((const short*)emb + (size_t)tok * EMB + ch);
        } else {
            const float* src = (const float*)emb + (size_t)tok * EMB + ch;
            #pragma unroll
            for (int j = 0; j < 8; j++) v[j] = f2bf(src[j]);
        }
        *(bf16x8*)(eseq + (size_t)u * EMB + ch) = v;
    }
}

// ---------------------------------------------------------------------------
// K2: intra-XCD persistent scan. Weights in LDS (bf16, 96KB). 32 wgs of 512
// threads (8 waves, 2/SIMD). Wave pairs split K; LDS partial-sum exchange.
// ---------------------------------------------------------------------------
__global__ __launch_bounds__(512) void k2_lstm(
    const void* __restrict__ w_hh, const void* __restrict__ w_ih,
    const void* __restrict__ b_ih, const void* __restrict__ b_hh,
    const void* __restrict__ emb, const short* __restrict__ eseq,
    short* __restrict__ hbuf, int* __restrict__ sync, int* __restrict__ flags)
{
    // 96 slots (nt*24+kk) x 64 lanes x 16B = 98,304 B of bf16 weight frags
    __shared__ short lds_w[96 * 64 * 8];
    __shared__ float xbuf[4 * 64 * 16];   // 16KB: partial accs from waves 4-7
    __shared__ float biasl[64];
    __shared__ int   sh_slot;

    const int t = threadIdx.x;

    // ---- XCD leader claim (round-9/10 verified; startup only).
    // Pigeonhole: 8*31 = 248 < 256 grid => some XCD always reaches NPART. ----
    if (t == 0) {
        unsigned xcd;
        asm volatile("s_getreg_b32 %0, hwreg(HW_REG_XCC_ID)" : "=s"(xcd));
        xcd &= 7u;
        int c = atomicAdd(&sync[8 + xcd], 1);
        if (c == NPART - 1) atomicCAS(&sync[0], 0, (int)xcd + 1);
        int L;
        while ((L = atomicAdd(&sync[0], 0)) == 0)
            __builtin_amdgcn_s_sleep(8);
        sh_slot = (L == (int)xcd + 1 && c < NPART) ? c : -1;
    }
    __syncthreads();
    const int g = sh_slot;
    if (g < 0) return;

    const bool isbf = detect_bf16(emb);
    const int lane = t & 63;
    const int w    = t >> 6;        // 0..7
    const int q    = w & 3;         // batch quadrant
    const int ks   = w >> 2;        // K-half: 0 = e0-3+h0-7, 1 = e4-7+h8-15
    const int col  = lane & 15;
    const int quad = lane >> 4;

    // ---- stage weight fragments into LDS (bf16), once ----
    // slot = nt*24 + kk; kk 0..15 = W_hh (k=kk*32+q*8), kk 16..23 = W_ih.
    for (int item = t; item < 96 * 64; item += 512) {
        int slot = item >> 6;
        int ln   = item & 63;
        int nt   = slot / 24;
        int kk   = slot % 24;
        int c    = ln & 15, qq = ln >> 4;
        size_t grow = (size_t)(nt * HID + g * WCOLS + c);
        bf16x8 v;
        if (kk < 16) v = ldfrag(w_hh, grow * HID + kk * 32 + qq * 8, isbf);
        else         v = ldfrag(w_ih, grow * EMB + (kk - 16) * 32 + qq * 8, isbf);
        *(bf16x8*)(lds_w + (size_t)item * 8) = v;
    }
    if (t < 64) {
        int grow = (t >> 4) * HID + g * WCOLS + (t & 15);
        biasl[t] = rd(b_ih, grow, isbf) + rd(b_hh, grow, isbf);
    }
    __syncthreads();
    const float bI = biasl[col],      bF = biasl[16 + col];
    const float bG = biasl[32 + col], bO = biasl[48 + col];

    // per-lane base into the LDS frag table
    const short* lwl = lds_w + lane * 8;
#define LWF(nt, kk) (*(const bf16x8*)(lwl + (size_t)(((nt) * 24 + (kk)) * 64) * 8))

    float cre[4] = {0.f, 0.f, 0.f, 0.f};   // live in ks==0 waves only

    const int eoff = ks * 4;   // this wave's e-chunk base (global chunk id)
    const int hoff = ks * 8;   // this wave's h-chunk base

    const short* eptr = eseq + (size_t)(q * 16 + col) * EMB + quad * 8;
    const short* hrd  = hbuf + (size_t)(q * 16 + col) * HID + quad * 8;
    short*       hwr  = hbuf + (size_t)(BATCH * HID)
                      + (size_t)(q * 16 + quad * 4) * HID + g * WCOLS + col;
    float* xb = xbuf + (size_t)(q * 64 + lane) * 16;

    // ---- scan ----
    for (int step = 0; step < SEQ; step++) {
        // e A-frags + e-projection MFMAs (handshake-independent): both K-half
        // waves have 16 pre-poll MFMAs => poll latency hidden on every SIMD.
        bf16x8 ae[4];
        #pragma unroll
        for (int kk = 0; kk < 4; kk++)
            ae[kk] = *(const bf16x8*)(eptr + (eoff + kk) * 32);

        floatx4 a0 = (floatx4){0.f,0.f,0.f,0.f}, a1 = a0, a2 = a0, a3 = a0;
        #pragma unroll
        for (int kk = 0; kk < 4; kk++) {
            a0 = __builtin_amdgcn_mfma_f32_16x16x32_bf16(ae[kk], LWF(0, 16+eoff+kk), a0, 0,0,0);
            a1 = __builtin_amdgcn_mfma_f32_16x16x32_bf16(ae[kk], LWF(1, 16+eoff+kk), a1, 0,0,0);
            a2 = __builtin_amdgcn_mfma_f32_16x16x32_bf16(ae[kk], LWF(2, 16+eoff+kk), a2, 0,0,0);
            a3 = __builtin_amdgcn_mfma_f32_16x16x32_bf16(ae[kk], LWF(3, 16+eoff+kk), a3, 0,0,0);
        }

        // wave0's lanes 0..31 poll the 32 producer flags (RELAXED agent =
        // sc1 L1-bypass, no buffer_inv). Other waves wait at the barrier.
        if (step > 0 && w == 0 && lane < NPART) {
            int* fp = flags + (size_t)step * 64 + lane;
            int iters = 0;
            while (__hip_atomic_load(fp, __ATOMIC_RELAXED,
                                     __HIP_MEMORY_SCOPE_AGENT) == 0) {
                if (++iters > 16384) {
                    while (atomicAdd(fp, 0) == 0)
                        __builtin_amdgcn_s_sleep(8);
                    break;
                }
            }
        }
        __builtin_amdgcn_sched_barrier(0);
        __syncthreads();       // barrier 1: h(step-1) published & in L2

        // this wave's 8 h-chunks, issued back-to-back
        bf16x8 ah[8];
        #pragma unroll
        for (int kk = 0; kk < 8; kk++)
            ah[kk] = *(const bf16x8*)(hrd + (hoff + kk) * 32);
        #pragma unroll
        for (int kk = 0; kk < 8; kk++) {
            a0 = __builtin_amdgcn_mfma_f32_16x16x32_bf16(ah[kk], LWF(0, hoff+kk), a0, 0,0,0);
            a1 = __builtin_amdgcn_mfma_f32_16x16x32_bf16(ah[kk], LWF(1, hoff+kk), a1, 0,0,0);
            a2 = __builtin_amdgcn_mfma_f32_16x16x32_bf16(ah[kk], LWF(2, hoff+kk), a2, 0,0,0);
            a3 = __builtin_amdgcn_mfma_f32_16x16x32_bf16(ah[kk], LWF(3, hoff+kk), a3, 0,0,0);
        }

        // waves 4-7: export partial sums (16 f32/lane, contiguous)
        if (ks == 1) {
            *(floatx4*)(xb + 0)  = a0;
            *(floatx4*)(xb + 4)  = a1;
            *(floatx4*)(xb + 8)  = a2;
            *(floatx4*)(xb + 12) = a3;
        }
        __syncthreads();       // barrier 2: partials visible

        if (ks == 0) {
            floatx4 p0 = *(const floatx4*)(xb + 0);
            floatx4 p1 = *(const floatx4*)(xb + 4);
            floatx4 p2 = *(const floatx4*)(xb + 8);
            floatx4 p3 = *(const floatx4*)(xb + 12);
            // in-register epilogue (combine + gates)
            #pragma unroll
            for (int r = 0; r < 4; r++) {
                float iv = sigm(a0[r] + p0[r] + bI);
                float fv = sigm(a1[r] + p1[r] + bF);
                float gv = tanh_fast(a2[r] + p2[r] + bG);
                float ov = sigm(a3[r] + p3[r] + bO);
                cre[r] = fv * cre[r] + iv * gv;
                float h = ov * tanh_fast(cre[r]);
                hwr[(size_t)r * HID] = f2bf(h);
            }
        }

        // barrier 3 drains every wave's vmcnt before s_barrier => all
        // h-stores committed to L2 when t0 publishes.
        __syncthreads();
        if (t == 0)
            __hip_atomic_store(flags + (size_t)(step + 1) * 64 + g, 1,
                               __ATOMIC_RELAXED, __HIP_MEMORY_SCOPE_AGENT);

        eptr += (size_t)BATCH * EMB;
        hrd  += (size_t)BATCH * HID;
        hwr  += (size_t)BATCH * HID;
    }
#undef LWF
}

// ---------------------------------------------------------------------------
// K3: logits = h_seq * W_fc^T + b_fc -> log_softmax(18). One token per thread.
// ---------------------------------------------------------------------------
__global__ __launch_bounds__(256) void k3_logits(
    const short* __restrict__ hbuf, const void* __restrict__ w_fc,
    const void* __restrict__ b_fc, const void* __restrict__ emb,
    void* __restrict__ out)
{
    __shared__ float Wf[NOUT][516];
    const bool isbf = detect_bf16(emb);
    const int t = threadIdx.x;
    for (int idx = t; idx < NOUT * 64; idx += 256) {
        int o = idx >> 6, ch = (idx & 63) * 8;
        #pragma unroll
        for (int j = 0; j < 8; j++)
            Wf[o][ch + j] = rd(w_fc, o * HID + ch + j, isbf);
    }
    __syncthreads();

    int u = blockIdx.x * 256 + t;              // u = s*64+b
    const short* hp = hbuf + (size_t)(u + BATCH) * HID;

    float acc[NOUT];
    #pragma unroll
    for (int o = 0; o < NOUT; o++) acc[o] = rd(b_fc, o, isbf);

    for (int ch = 0; ch < HID; ch += 8) {
        bf16x8 h8 = *(const bf16x8*)(hp + ch);
        float hf[8];
        #pragma unroll
        for (int j = 0; j < 8; j++) hf[j] = bf2f(h8[j]);
        #pragma unroll
        for (int o = 0; o < NOUT; o++) {
            floatx4 wa = *(const floatx4*)&Wf[o][ch];
            floatx4 wb = *(const floatx4*)&Wf[o][ch + 4];
            acc[o] += hf[0] * wa[0] + hf[1] * wa[1] + hf[2] * wa[2] + hf[3] * wa[3]
                    + hf[4] * wb[0] + hf[5] * wb[1] + hf[6] * wb[2] + hf[7] * wb[3];
        }
    }

    float mx = acc[0];
    #pragma unroll
    for (int o = 1; o < NOUT; o++) mx = fmaxf(mx, acc[o]);
    float s = 0.f;
    #pragma unroll
    for (int o = 0; o < NOUT; o++) s += __expf(acc[o] - mx);
    float lse = mx + __logf(s);

    int b = u & 63, sq = u >> 6;
    size_t base = (size_t)b * (SEQ * NOUT) + (size_t)sq * NOUT;
    if (isbf) {
        short* op = (short*)out + base;
        #pragma unroll
        for (int o = 0; o < NOUT; o++) op[o] = f2bf(acc[o] - lse);
    } else {
        float* op = (float*)out + base;
        #pragma unroll
        for (int o = 0; o < NOUT; o++) op[o] = acc[o] - lse;
    }
}

// ---------------------------------------------------------------------------
extern "C" void kernel_launch(void* const* d_in, const int* in_sizes, int n_in,
                              void* d_out, int out_size, void* d_ws, size_t ws_size,
                              hipStream_t stream) {
    const int*  x   = (const int*)d_in[0];
    const void* emb = d_in[1];
    const void* wih = d_in[2];
    const void* whh = d_in[3];
    const void* bih = d_in[4];
    const void* bhh = d_in[5];
    const void* wfc = d_in[6];
    const void* bfc = d_in[7];

    char*  ws    = (char*)d_ws;
    int*   sync  = (int*)ws;
    int*   flags = (int*)(ws + 4096);
    const size_t flagsz = (size_t)(SEQ + 1) * 64 * sizeof(int);   // 131.3 KB
    short* hbuf  = (short*)(ws + 4096 + ((flagsz + 255) & ~(size_t)255));
    short* eseq  = (short*)((char*)hbuf + (size_t)(SEQ + 1) * BATCH * HID * 2);

    (void)hipMemsetAsync(sync, 0, 4096, stream);                    // claim
    (void)hipMemsetAsync(flags, 0, flagsz, stream);                 // flags = 0
    (void)hipMemsetAsync(hbuf, 0, (size_t)BATCH * HID * 2, stream); // h_0 = 0

    k0_gather<<<1024, 256, 0, stream>>>(x, emb, eseq);
    k2_lstm<<<256, 512, 0, stream>>>(whh, wih, bih, bhh, emb, eseq,
                                     hbuf, sync, flags);
    k3_logits<<<128, 256, 0, stream>>>(hbuf, wfc, bfc, emb, d_out);
}